// Round 4
// baseline (217.854 us; speedup 1.0000x reference)
//
#include <hip/hip_runtime.h>
#include <hip/hip_bf16.h>

#define NROWS  8192
#define DIM    256
#define NCLASS 512
#define NBLK   512          // grid size == exact co-resident capacity (2 blocks/CU)
#define MARGIN 0.3f

#define ORD_NEGINF 0x007FFFFFu  // f2ord(-inf)
#define ORD_POSINF 0xFF800000u  // f2ord(+inf)

using bf16x8 = __attribute__((ext_vector_type(8))) short;
using f32x4  = __attribute__((ext_vector_type(4))) float;

__device__ inline ushort f2bf(float f) {
    __hip_bfloat16 h = __float2bfloat16(f);
    return *reinterpret_cast<ushort*>(&h);
}
__device__ inline float bf2f(ushort u) {
    return __uint_as_float(((unsigned)u) << 16);
}
// Order-preserving float<->uint transform: bitwise atomicMax/Min == float max/min.
__device__ inline unsigned f2ord(float f) {
    unsigned b = __float_as_uint(f);
    return (b & 0x80000000u) ? ~b : (b | 0x80000000u);
}
__device__ inline float ord2f(unsigned u) {
    return __uint_as_float((u & 0x80000000u) ? (u & 0x7FFFFFFFu) : ~u);
}
__device__ inline void ld16_g2l(const void* g, void* l) {
    __builtin_amdgcn_global_load_lds(
        (const __attribute__((address_space(1))) unsigned int*)g,
        (__attribute__((address_space(3))) unsigned int*)l, 16, 0, 0);
}

// ---- workspace layout (bytes) ----
#define XB_OFF   0u          // 4 MB   bf16 rows (original order)
#define SQU_OFF  4194304u    // 32 KB  ||x||^2 (original order)
#define PRM_OFF  4227072u    // 32 KB  perm: sorted slot -> original row
#define SQS_OFF  4259840u    // 32 KB  sorted ||x||^2
#define TGS_OFF  4292608u    // 32 KB  sorted class id
#define PMX_OFF  4325376u    // 32 KB  ordered-uint max over positives of (sqc-2acc)
#define NMN_OFF  4358144u    // 32 KB  ordered-uint min over negatives
#define META_OFF 4390912u    // 4 KB   bins[512] + barrier counters (memset to 0)

struct SM {
    char  buf[2][16384];  // B stage buffers: 32 cols x 512 B, 16B-chunk xor-swizzled
    float sqc[512];       // per-col ||x||^2 for this block's 512-col chunk (sorted)
    int   tgc[512];       // per-col class (sorted)
    int   prm[512];       // per-col original row (for DMA source addressing)
    int   tga[256];       // per-row class for block's 256 rows (sorted)
};

// Grid barrier: all NBLK blocks are co-resident by construction (see launch math).
__device__ inline void grid_barrier(unsigned* cnt) {
    __syncthreads();
    if (threadIdx.x == 0) {
        __threadfence();                 // release: prior writes visible device-wide
        atomicAdd(cnt, 1u);
        while (atomicAdd(cnt, 0u) < NBLK) __builtin_amdgcn_s_sleep(2);
        __threadfence();                 // acquire
    }
    __syncthreads();
}

__global__ __launch_bounds__(256, 2) void fused_kernel(
    const float* __restrict__ in, const int* __restrict__ tgt,
    ushort* __restrict__ xb, float* __restrict__ squ,
    int* __restrict__ perm, float* __restrict__ sqs, int* __restrict__ tgts,
    unsigned* __restrict__ pmax, unsigned* __restrict__ nmin,
    int* __restrict__ bins, unsigned* __restrict__ bar1,
    unsigned* __restrict__ bar2, unsigned* __restrict__ ticket,
    float* __restrict__ out)
{
    __shared__ SM sm;
    __shared__ unsigned lastflag;
    const int b    = blockIdx.x;
    const int tid  = threadIdx.x;
    const int wave = tid >> 6;
    const int lane = tid & 63;
    const int l15  = lane & 15;
    const int quad = lane >> 4;

    // ================= Phase 1: normalize 16 rows, histogram, init reduce arrays
#pragma unroll
    for (int i = 0; i < 4; ++i) {
        int row = b * 16 + wave * 4 + i;
        float4 v = ((const float4*)(in + (size_t)row * DIM))[lane];
        float ss = v.x * v.x + v.y * v.y + v.z * v.z + v.w * v.w;
#pragma unroll
        for (int m = 1; m < 64; m <<= 1) ss += __shfl_xor(ss, m, 64);
        float inv = 1.0f / (sqrtf(ss) + 1e-12f);
        ushort4 st;
        st.x = f2bf(v.x * inv); st.y = f2bf(v.y * inv);
        st.z = f2bf(v.z * inv); st.w = f2bf(v.w * inv);
        ((ushort4*)(xb + (size_t)row * DIM))[lane] = st;
        float a0 = bf2f(st.x), a1 = bf2f(st.y), a2 = bf2f(st.z), a3 = bf2f(st.w);
        float s2 = a0 * a0 + a1 * a1 + a2 * a2 + a3 * a3;
#pragma unroll
        for (int m = 1; m < 64; m <<= 1) s2 += __shfl_xor(s2, m, 64);
        if (lane == 0) {
            squ[row]  = s2;
            pmax[row] = ORD_NEGINF;
            nmin[row] = ORD_POSINF;
            atomicAdd(&bins[tgt[row]], 1);
        }
    }
    grid_barrier(bar1);

    // ================= Phase 1.5: block 0 scans bins, builds class-sorted perm
    if (b == 0) {
        int* sc  = (int*)sm.buf[0];
        int* cur = sc + NCLASS;
        const int c0 = tid, c1 = tid + 256;
        sc[c0] = atomicAdd(&bins[c0], 0);   // coherent read of cross-block atomics
        sc[c1] = atomicAdd(&bins[c1], 0);
        __syncthreads();
        int n0 = sc[c0], n1 = sc[c1];
        for (int ofs = 1; ofs < NCLASS; ofs <<= 1) {
            int v0 = (c0 >= ofs) ? sc[c0 - ofs] : 0;
            int v1 = (c1 >= ofs) ? sc[c1 - ofs] : 0;
            __syncthreads();
            sc[c0] += v0; sc[c1] += v1;
            __syncthreads();
        }
        cur[c0] = sc[c0] - n0;  // exclusive start
        cur[c1] = sc[c1] - n1;
        __syncthreads();
        for (int it = 0; it < NROWS / 256; ++it) {
            int r = it * 256 + tid;
            int c = tgt[r];
            int slot = atomicAdd(&cur[c], 1);
            perm[slot] = r;
            sqs[slot]  = squ[r];
            tgts[slot] = c;
        }
    }
    grid_barrier(bar2);

    // ================= Phase 2: fused gram + hard-pos/hard-neg (round-3 structure)
    const int bx = b >> 4;              // 32 row-blocks of 256 sorted rows
    const int by = b & 15;              // 16 col-chunks of 512 sorted cols
    const int mbase = bx * 256 + wave * 64;
    const int nbase = by * 512;

    {   // stage sorted metadata for the whole chunk
        int c = tid * 2;
        sm.sqc[c]     = sqs[nbase + c];
        sm.sqc[c + 1] = sqs[nbase + c + 1];
        sm.tgc[c]     = tgts[nbase + c];
        sm.tgc[c + 1] = tgts[nbase + c + 1];
        sm.prm[c]     = perm[nbase + c];
        sm.prm[c + 1] = perm[nbase + c + 1];
        sm.tga[tid]   = tgts[bx * 256 + tid];
    }
    __syncthreads();

    // A fragments: 4 tiles x full K=256, gathered via perm
    bf16x8 afrag[4][8];
#pragma unroll
    for (int a = 0; a < 4; ++a) {
        int grow = perm[mbase + a * 16 + l15];
        const ushort* arow = xb + (size_t)grow * DIM + quad * 8;
#pragma unroll
        for (int kk = 0; kk < 8; ++kk)
            afrag[a][kk] = *(const bf16x8*)(arow + kk * 32);
    }
    const int rlo = sm.tga[wave * 64];
    const int rhi = sm.tga[wave * 64 + 63];

    const int colh = lane >> 5, c31 = lane & 31;
    const char* xb_b = (const char*)xb;

    // Prologue: DMA stage 0. Region i holds cols {2i,2i+1}; lane writes +lane*16,
    // so physical slot c31 of col (2i+colh) must hold logical chunk c31^(col&7),
    // compensated on the global source address.
    {
#pragma unroll
        for (int j = 0; j < 4; ++j) {
            int i = wave * 4 + j;
            int col = 2 * i + colh;
            int prow = sm.prm[col];
            ld16_g2l(xb_b + (size_t)prow * 512 + ((c31 ^ (col & 7)) << 4),
                     sm.buf[0] + i * 1024);
        }
    }
    __syncthreads();   // drains DMA + afrag loads

    float pm[16], nm[16];
#pragma unroll
    for (int j = 0; j < 16; ++j) { pm[j] = -__builtin_inff(); nm[j] = __builtin_inff(); }

#pragma unroll 2
    for (int s = 0; s < 16; ++s) {
        if (s < 15) {   // issue stage s+1 (lands during this stage's compute)
            char* lbase = sm.buf[(s + 1) & 1];
#pragma unroll
            for (int j = 0; j < 4; ++j) {
                int i = wave * 4 + j;
                int col = 2 * i + colh;
                int prow = sm.prm[(s + 1) * 32 + col];
                ld16_g2l(xb_b + (size_t)prow * 512 + ((c31 ^ (col & 7)) << 4),
                         lbase + i * 1024);
            }
        }
        const char* bufc = sm.buf[s & 1];
#pragma unroll
        for (int u = 0; u < 2; ++u) {
            const int t16 = s * 32 + u * 16;
            bf16x8 bfrag[8];
#pragma unroll
            for (int kk = 0; kk < 8; ++kk)
                bfrag[kk] = *(const bf16x8*)(bufc + u * 8192 + l15 * 512 +
                                             (((quad + 4 * kk) ^ (l15 & 7)) << 4));
            f32x4 acc4[4];
#pragma unroll
            for (int a = 0; a < 4; ++a) {
                f32x4 acc = {0.f, 0.f, 0.f, 0.f};
#pragma unroll
                for (int kk = 0; kk < 8; ++kk)
                    acc = __builtin_amdgcn_mfma_f32_16x16x32_bf16(afrag[a][kk], bfrag[kk], acc, 0, 0, 0);
                acc4[a] = acc;
            }
            const float sqc = sm.sqc[t16 + l15];
            const int clo = sm.tgc[t16], chi = sm.tgc[t16 + 15];
            if (rlo <= chi && clo <= rhi) {
                const int tc = sm.tgc[t16 + l15];
#pragma unroll
                for (int a = 0; a < 4; ++a)
#pragma unroll
                    for (int i = 0; i < 4; ++i) {
                        const float v = fmaf(acc4[a][i], -2.0f, sqc);
                        const bool same = (sm.tga[wave * 64 + a * 16 + quad * 4 + i] == tc);
                        pm[a * 4 + i] = fmaxf(pm[a * 4 + i], same ? v : -__builtin_inff());
                        nm[a * 4 + i] = fminf(nm[a * 4 + i], same ? __builtin_inff() : v);
                    }
            } else {
#pragma unroll
                for (int a = 0; a < 4; ++a)
#pragma unroll
                    for (int i = 0; i < 4; ++i)
                        nm[a * 4 + i] = fminf(nm[a * 4 + i], fmaf(acc4[a][i], -2.0f, sqc));
            }
        }
        __syncthreads();
    }

#pragma unroll
    for (int m = 1; m < 16; m <<= 1) {
#pragma unroll
        for (int j = 0; j < 16; ++j) {
            pm[j] = fmaxf(pm[j], __shfl_xor(pm[j], m, 64));
            nm[j] = fminf(nm[j], __shfl_xor(nm[j], m, 64));
        }
    }
    if (l15 == 0) {
#pragma unroll
        for (int a = 0; a < 4; ++a)
#pragma unroll
            for (int i = 0; i < 4; ++i) {
                int r = mbase + a * 16 + quad * 4 + i;
                atomicMax(&pmax[r], f2ord(pm[a * 4 + i]));
                atomicMin(&nmin[r], f2ord(nm[a * 4 + i]));
            }
    }

    // ================= Phase 3: last-finishing block finalizes
    __syncthreads();   // block's atomics complete before ticket
    if (tid == 0) {
        __threadfence();
        unsigned arrived = atomicAdd(ticket, 1u) + 1;
        lastflag = (arrived == NBLK) ? 1u : 0u;
    }
    __syncthreads();
    if (lastflag) {
        double s = 0.0;
        for (int it = 0; it < NROWS / 256; ++it) {
            int r = it * 256 + tid;
            float pe = ord2f(atomicMax(&pmax[r], ORD_NEGINF));  // identity op = read
            float ne = ord2f(atomicMin(&nmin[r], ORD_POSINF));
            float ap = sqrtf(fmaxf(sqs[r] + pe, 0.0f));
            float an = (ne > 1e30f) ? (MARGIN + 1.0f) : sqrtf(fmaxf(sqs[r] + ne, 0.0f));
            float h  = fmaxf(ap - an + MARGIN, 0.0f);
            s += (double)h;
        }
#pragma unroll
        for (int m = 1; m < 64; m <<= 1) s += __shfl_xor(s, m, 64);
        double* shd = (double*)sm.buf[0];
        if (lane == 0) shd[wave] = s;
        __syncthreads();
        if (tid == 0) out[0] = (float)((shd[0] + shd[1] + shd[2] + shd[3]) / (double)NROWS);
    }
}

extern "C" void kernel_launch(void* const* d_in, const int* in_sizes, int n_in,
                              void* d_out, int out_size, void* d_ws, size_t ws_size,
                              hipStream_t stream) {
    const float* in  = (const float*)d_in[0];
    const int*   tgt = (const int*)d_in[1];
    float*       out = (float*)d_out;

    char* ws = (char*)d_ws;
    ushort*   xb     = (ushort*)(ws + XB_OFF);
    float*    squ    = (float*)(ws + SQU_OFF);
    int*      perm   = (int*)(ws + PRM_OFF);
    float*    sqs    = (float*)(ws + SQS_OFF);
    int*      tgts   = (int*)(ws + TGS_OFF);
    unsigned* pmax   = (unsigned*)(ws + PMX_OFF);
    unsigned* nmin   = (unsigned*)(ws + NMN_OFF);
    int*      bins   = (int*)(ws + META_OFF);
    unsigned* bar1   = (unsigned*)(ws + META_OFF + 2048);
    unsigned* bar2   = (unsigned*)(ws + META_OFF + 2052);
    unsigned* ticket = (unsigned*)(ws + META_OFF + 2056);

    hipMemsetAsync(ws + META_OFF, 0, 4096, stream);
    fused_kernel<<<NBLK, 256, 0, stream>>>(in, tgt, xb, squ, perm, sqs, tgts,
                                           pmax, nmin, bins, bar1, bar2, ticket, out);
}